// Round 6
// baseline (1405.523 us; speedup 1.0000x reference)
//
#include <hip/hip_runtime.h>

#define NODE 112
#define KP1 56
#define KP2 28
#define D1 256
#define D2 128
#define NBATCH 2048
#define RW 28      // rows per wave in phase-1 single-pass GEMM (112/4)
#define GR 7       // rows per group in phase-3/4b
#define CR 28      // fallback: rows per chunk

typedef const float* __restrict__ fp;

// ---------------- K0a: batch-independent attention logits s1[n], t1[n] ----------------
__global__ void k0a(fp Wp1, fp bp1, fp wa1, fp wb1,
                    float* __restrict__ s1, float* __restrict__ t1)
{
    int tid = threadIdx.x;
    int i = tid >> 1, half = tid & 1;
    float sa = 0.f, sb = 0.f;
    if (i < NODE) {
        for (int o = half*128; o < half*128 + 128; o++) {
            float h = Wp1[o*NODE + i] + bp1[o];
            sa += h * wa1[o];
            sb += h * wb1[o];
        }
    }
    sa += __shfl_xor(sa, 1, 64);
    sb += __shfl_xor(sb, 1, 64);
    if (i < NODE && half == 0) { s1[i] = sa; t1[i] = sb; }
}

// ---------------- K0b: hp [112][256], E1 [112][112], W2T [256][128] ----------------
__global__ void k0b(fp Wp1, fp bp1, fp ba1, fp Wp2,
                    const float* __restrict__ s1, const float* __restrict__ t1,
                    float* __restrict__ hp, float* __restrict__ E1, float* __restrict__ W2T)
{
    int g = blockIdx.x*blockDim.x + threadIdx.x;
    int stride = gridDim.x*blockDim.x;
    for (int e = g; e < NODE*D1; e += stride) {
        int j = e >> 8, o = e & 255;
        hp[e] = Wp1[o*NODE + j] + bp1[o];
    }
    float ba = ba1[0];
    for (int e = g; e < NODE*NODE; e += stride) {
        int i = e / NODE, j = e - i*NODE;
        E1[e] = expf(fmaxf(s1[i] + t1[j] + ba, 0.f));
    }
    for (int e = g; e < D1*D2; e += stride) {
        int d = e >> 7, o = e & 127;
        W2T[e] = Wp2[o*D1 + d];
    }
}

// wave-0 top-k with jax.lax.top_k tie semantics (equal value -> lower index first)
__device__ __forceinline__ void topk_wave(volatile float* sc, int n, int k,
                                          int* idxo, float* valo, int tid)
{
    for (int it = 0; it < k; it++) {
        float v = (tid < n) ? sc[tid] : -1e30f;
        int bi = tid;
        int j2 = tid + 64;
        if (j2 < n) { float v2 = sc[j2]; if (v2 > v) { v = v2; bi = j2; } }
        #pragma unroll
        for (int off = 32; off; off >>= 1) {
            float ov = __shfl_xor(v, off, 64);
            int   oi = __shfl_xor(bi, off, 64);
            if (ov > v || (ov == v && oi < bi)) { v = ov; bi = oi; }
        }
        if (tid == 0) { idxo[it] = bi; valo[it] = v; sc[bi] = -1e30f; }
    }
}

__device__ __forceinline__ float sigm(float v) { return 1.f/(1.f + expf(-v)); }

// ===================== FAST PATH =====================
__global__ __launch_bounds__(256, 2) void gnn_fast(
    fp x, fp Wpool1, fp bpool1, fp bp2, fp wa2, fp wb2, fp ba2,
    fp Wpool2, fp bpool2, fp Wfc1, fp bfc1, fp Wfc2, fp bfc2,
    fp hp, fp E1, fp W2T, float* __restrict__ out)
{
    // ovl: phase-1 awcF[112*112] (50176 B), then hg[56*256] (57344 B) after top-k.
    __shared__ __align__(16) float ovl[KP1*D1];
    __shared__ __align__(16) float awc2[KP1*KP1];   // att2 [56][56]
    __shared__ float rinv[NODE];
    __shared__ float sc1[NODE];
    __shared__ int   idx1[KP1];
    __shared__ float vals1[KP1];
    __shared__ int   sel[NODE];
    __shared__ float s2v[KP1], t2v[KP1];
    __shared__ float rs2inv[KP1];
    __shared__ float sc2[KP1];
    __shared__ int   idx2[KP2];
    __shared__ float vals2[KP2];
    __shared__ float hmean[D2];

    float* awcF = ovl;     // [112][112] attention weights (phase 1)
    float* hg   = ovl;     // [56][256] gathered h1 -> h2proj/h2 (after top-k)

    const int tid = threadIdx.x;
    const int lane = tid & 63, wave = tid >> 6;
    const int b = blockIdx.x;
    const float* xb = x + (size_t)b*NODE*NODE;

    const float4 wp1v = *(const float4*)(Wpool1 + 4*lane);
    const float bpool1v = bpool1[0];

    // ========== Phase 1 fill: awcF[i][j] = E1[i][j]*x[i][j], fold row sums ==========
    // 4 threads/row (seg = tid&3, 28 floats each). Coalesced (16 contiguous rows per
    // wave) and bank-conflict-free (8-lane group first-dword banks are a permutation).
    {
        const int seg = tid & 3;
        #pragma unroll
        for (int pass = 0; pass < 2; pass++) {
            const int i = (tid >> 2) + pass*64;
            float ps = 0.f;
            if (i < NODE) {
                const float4* Er = (const float4*)(E1 + i*NODE + seg*28);
                const float4* xr = (const float4*)(xb + i*NODE + seg*28);
                float4* ar = (float4*)(awcF + i*NODE + seg*28);
                #pragma unroll
                for (int q = 0; q < 7; q++) {
                    float4 e = Er[q], xv = xr[q];
                    float4 v = make_float4(e.x*xv.x, e.y*xv.y, e.z*xv.z, e.w*xv.w);
                    ar[q] = v;
                    ps += (v.x + v.y) + (v.z + v.w);
                }
            }
            ps += __shfl_xor(ps, 1, 64);
            ps += __shfl_xor(ps, 2, 64);
            if (i < NODE && seg == 0) rinv[i] = 1.f/ps;
        }
    }
    __syncthreads();

    // ========== Phase 1 GEMM: wave owns rows r0..r0+27; lane owns cols 4l..4l+3 ======
    // hp streamed from global exactly ONCE per wave (112 dwordx4). awcF reads are
    // wave-uniform LDS broadcasts. acc[28][4] (112 VGPR) doubles as h1 storage.
    const int r0 = wave*RW;
    float acc[RW][4];
    #pragma unroll
    for (int r = 0; r < RW; r++) { acc[r][0]=0.f; acc[r][1]=0.f; acc[r][2]=0.f; acc[r][3]=0.f; }
    #pragma unroll 2
    for (int jq = 0; jq < NODE/4; jq++) {
        const int j = jq*4;
        float4 hv0 = *(const float4*)(hp + (j+0)*D1 + 4*lane);
        float4 hv1 = *(const float4*)(hp + (j+1)*D1 + 4*lane);
        float4 hv2 = *(const float4*)(hp + (j+2)*D1 + 4*lane);
        float4 hv3 = *(const float4*)(hp + (j+3)*D1 + 4*lane);
        #pragma unroll
        for (int r = 0; r < RW; r++) {
            float4 a4 = *(const float4*)&awcF[(r0+r)*NODE + j];
            acc[r][0] += a4.x*hv0.x + a4.y*hv1.x + a4.z*hv2.x + a4.w*hv3.x;
            acc[r][1] += a4.x*hv0.y + a4.y*hv1.y + a4.z*hv2.y + a4.w*hv3.y;
            acc[r][2] += a4.x*hv0.z + a4.y*hv1.z + a4.z*hv2.z + a4.w*hv3.z;
            acc[r][3] += a4.x*hv0.w + a4.y*hv1.w + a4.z*hv2.w + a4.w*hv3.w;
        }
    }
    // epilogue: h1 = relu(acc*rinv + hp[i]) (kept in acc); pool1 scores
    #pragma unroll
    for (int r = 0; r < RW; r++) {
        const int i = r0 + r;
        const float ri = rinv[i];
        float4 hpi = *(const float4*)(hp + i*D1 + 4*lane);
        float v0 = fmaxf(acc[r][0]*ri + hpi.x, 0.f);
        float v1 = fmaxf(acc[r][1]*ri + hpi.y, 0.f);
        float v2 = fmaxf(acc[r][2]*ri + hpi.z, 0.f);
        float v3 = fmaxf(acc[r][3]*ri + hpi.w, 0.f);
        acc[r][0]=v0; acc[r][1]=v1; acc[r][2]=v2; acc[r][3]=v3;
        float p = v0*wp1v.x + v1*wp1v.y + v2*wp1v.z + v3*wp1v.w;
        #pragma unroll
        for (int off = 32; off; off >>= 1) p += __shfl_xor(p, off, 64);
        if (lane == 0) sc1[i] = sigm(p + bpool1v);
    }
    __syncthreads();   // all awcF reads done; sc1 complete

    // ========== top-56 (wave 0) + sel init (waves 2,3) ==========
    if (tid < 64) topk_wave(sc1, NODE, KP1, idx1, vals1, tid);
    else if (tid >= 128 && tid < 128 + NODE) sel[tid - 128] = -1;
    __syncthreads();
    if (tid < KP1) sel[idx1[tid]] = tid;
    __syncthreads();

    // ========== scatter selected h1 rows (scaled) into hg (overwrites awcF) ==========
    #pragma unroll
    for (int r = 0; r < RW; r++) {
        const int i = r0 + r;
        const int k = sel[i];                     // wave-uniform
        if (k >= 0) {
            const float vs = vals1[k];
            *(float4*)&hg[k*D1 + 4*lane] =
                make_float4(acc[r][0]*vs, acc[r][1]*vs, acc[r][2]*vs, acc[r][3]*vs);
        }
    }
    __syncthreads();

    // ========== Phase 3: h2proj = hg@W2T + bp2 -> hg cols 0..127 ==========
    {
        const int g = tid >> 5;          // 8 groups x 7 rows
        const int cs = tid & 31;         // cols 4cs..4cs+3 of 128
        float acc2[GR][4];
        #pragma unroll
        for (int r = 0; r < GR; r++) { acc2[r][0]=0.f; acc2[r][1]=0.f; acc2[r][2]=0.f; acc2[r][3]=0.f; }
        #pragma unroll 2
        for (int dq = 0; dq < D1/4; dq++) {
            const int d = dq*4;
            float4 w0 = *(const float4*)(W2T + (d+0)*D2 + 4*cs);
            float4 w1 = *(const float4*)(W2T + (d+1)*D2 + 4*cs);
            float4 w2 = *(const float4*)(W2T + (d+2)*D2 + 4*cs);
            float4 w3 = *(const float4*)(W2T + (d+3)*D2 + 4*cs);
            #pragma unroll
            for (int r = 0; r < GR; r++) {
                float4 a4 = *(const float4*)&hg[(g*GR+r)*D1 + d];
                acc2[r][0] += a4.x*w0.x + a4.y*w1.x + a4.z*w2.x + a4.w*w3.x;
                acc2[r][1] += a4.x*w0.y + a4.y*w1.y + a4.z*w2.y + a4.w*w3.y;
                acc2[r][2] += a4.x*w0.z + a4.y*w1.z + a4.z*w2.z + a4.w*w3.z;
                acc2[r][3] += a4.x*w0.w + a4.y*w1.w + a4.z*w2.w + a4.w*w3.w;
            }
        }
        float4 b2 = *(const float4*)(bp2 + 4*cs);
        __syncthreads();   // all hg reads complete before overwrite
        #pragma unroll
        for (int r = 0; r < GR; r++) {
            *(float4*)&hg[(g*GR+r)*D1 + 4*cs] =
                make_float4(acc2[r][0]+b2.x, acc2[r][1]+b2.y, acc2[r][2]+b2.z, acc2[r][3]+b2.w);
        }
    }
    __syncthreads();

    // ========== Phase 3.5: s2[n], t2[n] ==========
    if (tid < 4*KP1) {
        int row = tid >> 2, seg = tid & 3;       // 4 threads/row, 32 cols each
        float sa = 0.f, sb = 0.f;
        #pragma unroll
        for (int q = 0; q < 8; q++) {
            float4 hv = *(const float4*)&hg[row*D1 + seg*32 + q*4];
            float4 va = *(const float4*)(wa2 + seg*32 + q*4);
            float4 vb = *(const float4*)(wb2 + seg*32 + q*4);
            sa += hv.x*va.x + hv.y*va.y + hv.z*va.z + hv.w*va.w;
            sb += hv.x*vb.x + hv.y*vb.y + hv.z*vb.z + hv.w*vb.w;
        }
        sa += __shfl_xor(sa, 1, 64); sa += __shfl_xor(sa, 2, 64);
        sb += __shfl_xor(sb, 1, 64); sb += __shfl_xor(sb, 2, 64);
        if (seg == 0) { s2v[row] = sa; t2v[row] = sb; }
    }
    __syncthreads();

    // ========== Phase 4a: att2 fill (pool1 row-norm cancels) + row sums ==========
    if (tid < 4*KP1) {
        int rloc = tid >> 2, seg = tid & 3;      // 4 threads/row, 14 cols each
        float ps = 0.f;
        int gi = idx1[rloc];
        float srow = s2v[rloc];
        const float ba2v = ba2[0];
        const float* xrow = xb + gi*NODE;
        float* arow = awc2 + rloc*KP1 + seg*14;
        #pragma unroll
        for (int q = 0; q < 14; q++) {
            int j = seg*14 + q;
            float e = fmaxf(srow + t2v[j] + ba2v, 0.f);
            float v = expf(e) * xrow[idx1[j]];
            arow[q] = v;
            ps += v;
        }
        ps += __shfl_xor(ps, 1, 64); ps += __shfl_xor(ps, 2, 64);
        if (seg == 0) rs2inv[rloc] = 1.f/ps;
    }
    __syncthreads();

    // ========== Phase 4b: h2 = relu(att2@h2proj + h2proj) -> hg cols 128..255 ==========
    {
        const int g = tid >> 5, cs = tid & 31;
        float acc3[GR][4];
        #pragma unroll
        for (int r = 0; r < GR; r++) { acc3[r][0]=0.f; acc3[r][1]=0.f; acc3[r][2]=0.f; acc3[r][3]=0.f; }
        #pragma unroll 2
        for (int lq = 0; lq < KP1/4; lq++) {
            const int l = lq*4;
            float4 p0 = *(const float4*)&hg[(l+0)*D1 + 4*cs];
            float4 p1 = *(const float4*)&hg[(l+1)*D1 + 4*cs];
            float4 p2 = *(const float4*)&hg[(l+2)*D1 + 4*cs];
            float4 p3 = *(const float4*)&hg[(l+3)*D1 + 4*cs];
            #pragma unroll
            for (int r = 0; r < GR; r++) {
                float4 a4 = *(const float4*)&awc2[(g*GR+r)*KP1 + l];
                acc3[r][0] += a4.x*p0.x + a4.y*p1.x + a4.z*p2.x + a4.w*p3.x;
                acc3[r][1] += a4.x*p0.y + a4.y*p1.y + a4.z*p2.y + a4.w*p3.y;
                acc3[r][2] += a4.x*p0.z + a4.y*p1.z + a4.z*p2.z + a4.w*p3.z;
                acc3[r][3] += a4.x*p0.w + a4.y*p1.w + a4.z*p2.w + a4.w*p3.w;
            }
        }
        const float4 wp2v = *(const float4*)(Wpool2 + 4*cs);
        const float bpool2v = bpool2[0];
        #pragma unroll
        for (int r = 0; r < GR; r++) {
            int row = g*GR + r;
            float ri = rs2inv[row];
            float4 hpj = *(const float4*)&hg[row*D1 + 4*cs];       // residual (cols 0..127)
            float v0 = fmaxf(acc3[r][0]*ri + hpj.x, 0.f);
            float v1 = fmaxf(acc3[r][1]*ri + hpj.y, 0.f);
            float v2 = fmaxf(acc3[r][2]*ri + hpj.z, 0.f);
            float v3 = fmaxf(acc3[r][3]*ri + hpj.w, 0.f);
            *(float4*)&hg[row*D1 + D2 + 4*cs] = make_float4(v0, v1, v2, v3);
            float p = v0*wp2v.x + v1*wp2v.y + v2*wp2v.z + v3*wp2v.w;
            p += __shfl_xor(p, 16, 64); p += __shfl_xor(p, 8, 64);
            p += __shfl_xor(p, 4, 64);  p += __shfl_xor(p, 2, 64);
            p += __shfl_xor(p, 1, 64);
            if (cs == 0) sc2[row] = sigm(p + bpool2v);
        }
    }
    __syncthreads();

    // ========== top-28 ==========
    if (tid < 64) topk_wave(sc2, KP1, KP2, idx2, vals2, tid);
    __syncthreads();

    // ========== Phase 6: weighted mean over pooled nodes ==========
    if (tid < D2) {
        float m = 0.f;
        for (int k = 0; k < KP2; k++) m += hg[idx2[k]*D1 + D2 + tid] * vals2[k];
        hmean[tid] = m * (1.f/28.f);
    }
    __syncthreads();

    // ========== Phase 7: FC head ==========
    if (tid < 64) {
        float s = 0.f;
        #pragma unroll
        for (int q = 0; q < 32; q++) {
            float4 w = *(const float4*)(Wfc1 + tid*D2 + q*4);
            s += hmean[q*4+0]*w.x + hmean[q*4+1]*w.y + hmean[q*4+2]*w.z + hmean[q*4+3]*w.w;
        }
        s = fmaxf(s + bfc1[tid], 0.f);
        float v = s * Wfc2[tid];
        #pragma unroll
        for (int off = 32; off; off >>= 1) v += __shfl_xor(v, off, 64);
        if (tid == 0) out[b] = v + bfc2[0];
    }
}

// ===================== FALLBACK (round-3 kernel, passed) =====================
__global__ __launch_bounds__(256) void gnn_fallback(
    fp x, fp Wp1, fp bp1, fp wa1, fp wb1, fp ba1,
    fp Wpool1, fp bpool1, fp Wp2, fp bp2, fp wa2, fp wb2, fp ba2,
    fp Wpool2, fp bpool2, fp Wfc1, fp bfc1, fp Wfc2, fp bfc2,
    float* __restrict__ out)
{
    __shared__ __align__(16) float hg[KP1*D1];
    __shared__ __align__(16) float awc[CR*NODE];
    __shared__ float s1v[NODE], t1v[NODE];
    __shared__ float sc1[NODE];
    __shared__ float rsc[KP1];
    __shared__ float redc[4*CR];
    __shared__ int   idx1[KP1];
    __shared__ float vals1[KP1];
    __shared__ float s2v[KP1], t2v[KP1];
    __shared__ float sc2[KP1];
    __shared__ int   idx2[KP2];
    __shared__ float vals2[KP2];
    __shared__ float hmean[D2];

    const int tid = threadIdx.x;
    const int lane = tid & 63, wave = tid >> 6;
    const int b = blockIdx.x;
    const float* xb = x + (size_t)b*NODE*NODE;

    const float wpool1v = Wpool1[tid];
    const float bpool1v = bpool1[0];
    const float ba1v    = ba1[0];
    const float* wrow = Wp1 + tid*NODE;
    const float bp1v = bp1[tid];

    if (tid < NODE) {
        float sa = 0.f, sb = 0.f;
        for (int o = 0; o < D1; o++) {
            float h = Wp1[o*NODE + tid] + bp1[o];
            sa += h * wa1[o];
            sb += h * wb1[o];
        }
        s1v[tid] = sa; t1v[tid] = sb;
    }
    __syncthreads();

    for (int c = 0; c < NODE/CR; c++) {
        const int i0 = c*CR;
        for (int e = tid; e < CR*NODE; e += 256) {
            int r = e / NODE, j = e - r*NODE;
            int i = i0 + r;
            float ee = fmaxf(s1v[i] + t1v[j] + ba1v, 0.f);
            awc[e] = expf(ee) * xb[i*NODE + j];
        }
        __syncthreads();
        if (tid < CR) {
            float s = 0.f;
            for (int j = 0; j < NODE; j++) s += awc[tid*NODE + j];
            rsc[tid] = s;
        }
        __syncthreads();
        float acc[CR];
        #pragma unroll
        for (int r = 0; r < CR; r++) acc[r] = 0.f;
        for (int jg = 0; jg < NODE/4; jg++) {
            float4 w = *(const float4*)(wrow + jg*4);
            float h0 = w.x + bp1v, h1 = w.y + bp1v, h2 = w.z + bp1v, h3 = w.w + bp1v;
            #pragma unroll
            for (int r = 0; r < CR; r++) {
                float4 a4 = *(const float4*)&awc[r*NODE + jg*4];
                acc[r] += a4.x*h0 + a4.y*h1 + a4.z*h2 + a4.w*h3;
            }
        }
        float part[CR];
        #pragma unroll
        for (int r = 0; r < CR; r++) {
            float hpi = wrow[i0 + r] + bp1v;
            float h1v = fmaxf(acc[r]/rsc[r] + hpi, 0.f);
            part[r] = h1v * wpool1v;
        }
        #pragma unroll
        for (int r = 0; r < CR; r++) {
            float v = part[r];
            #pragma unroll
            for (int off = 32; off; off >>= 1) v += __shfl_xor(v, off, 64);
            if (lane == 0) redc[wave*CR + r] = v;
        }
        __syncthreads();
        if (tid < CR) {
            float s = redc[tid] + redc[CR+tid] + redc[2*CR+tid] + redc[3*CR+tid];
            sc1[i0 + tid] = sigm(s + bpool1v);
        }
        __syncthreads();
    }

    if (tid < 64) topk_wave(sc1, NODE, KP1, idx1, vals1, tid);
    __syncthreads();

    for (int c = 0; c < KP1/CR; c++) {
        const int k0 = c*CR;
        for (int e = tid; e < CR*NODE; e += 256) {
            int r = e / NODE, j = e - r*NODE;
            int i = idx1[k0 + r];
            float ee = fmaxf(s1v[i] + t1v[j] + ba1v, 0.f);
            awc[e] = expf(ee) * xb[i*NODE + j];
        }
        __syncthreads();
        if (tid < CR) {
            float s = 0.f;
            for (int j = 0; j < NODE; j++) s += awc[tid*NODE + j];
            rsc[tid] = s;
        }
        __syncthreads();
        float acc[CR];
        #pragma unroll
        for (int r = 0; r < CR; r++) acc[r] = 0.f;
        for (int jg = 0; jg < NODE/4; jg++) {
            float4 w = *(const float4*)(wrow + jg*4);
            float h0 = w.x + bp1v, h1 = w.y + bp1v, h2 = w.z + bp1v, h3 = w.w + bp1v;
            #pragma unroll
            for (int r = 0; r < CR; r++) {
                float4 a4 = *(const float4*)&awc[r*NODE + jg*4];
                acc[r] += a4.x*h0 + a4.y*h1 + a4.z*h2 + a4.w*h3;
            }
        }
        #pragma unroll
        for (int r = 0; r < CR; r++) {
            int k = k0 + r;
            float hpi = wrow[idx1[k]] + bp1v;
            float h1v = fmaxf(acc[r]/rsc[r] + hpi, 0.f);
            hg[k*D1 + tid] = h1v * vals1[k];
        }
        __syncthreads();
    }

    {
        const int half = tid >> 7, o = tid & 127;
        const float* w2row = Wp2 + o*D1;
        float acc2[CR];
        #pragma unroll
        for (int r = 0; r < CR; r++) acc2[r] = 0.f;
        for (int d4 = 0; d4 < D1; d4 += 4) {
            float4 w = *(const float4*)(w2row + d4);
            #pragma unroll
            for (int r = 0; r < CR; r++) {
                float4 h4 = *(const float4*)&hg[(half*CR + r)*D1 + d4];
                acc2[r] += h4.x*w.x + h4.y*w.y + h4.z*w.z + h4.w*w.w;
            }
        }
        __syncthreads();
        float bp2v = bp2[o];
        #pragma unroll
        for (int r = 0; r < CR; r++)
            hg[(half*CR + r)*D1 + o] = acc2[r] + bp2v;
    }
    __syncthreads();

    if (tid < KP1) {
        float sa = 0.f, sb = 0.f;
        for (int o2 = 0; o2 < D2; o2++) {
            float hv = hg[tid*D1 + o2];
            sa += hv * wa2[o2];
            sb += hv * wb2[o2];
        }
        s2v[tid] = sa; t2v[tid] = sb;
    }
    __syncthreads();

    {
        const float ba2v = ba2[0];
        for (int e = tid; e < KP1*KP1; e += 256) {
            int i = e / KP1, j = e - i*KP1;
            float ee = fmaxf(s2v[i] + t2v[j] + ba2v, 0.f);
            awc[e] = expf(ee) * xb[idx1[i]*NODE + idx1[j]];
        }
    }
    __syncthreads();
    if (tid < KP1) {
        float s = 0.f;
        for (int j = 0; j < KP1; j++) s += awc[tid*KP1 + j];
        rsc[tid] = s;
    }
    __syncthreads();

    {
        const int half = tid >> 7, o = tid & 127;
        float acc3[CR];
        #pragma unroll
        for (int r = 0; r < CR; r++) acc3[r] = 0.f;
        for (int l4 = 0; l4 < KP1; l4 += 4) {
            float p0 = hg[(l4+0)*D1 + o];
            float p1 = hg[(l4+1)*D1 + o];
            float p2 = hg[(l4+2)*D1 + o];
            float p3 = hg[(l4+3)*D1 + o];
            #pragma unroll
            for (int r = 0; r < CR; r++) {
                float4 a4 = *(const float4*)&awc[(half*CR + r)*KP1 + l4];
                acc3[r] += a4.x*p0 + a4.y*p1 + a4.z*p2 + a4.w*p3;
            }
        }
        const float wpool2v = Wpool2[o];
        float part2[CR];
        #pragma unroll
        for (int r = 0; r < CR; r++) {
            int n = half*CR + r;
            float h2v = fmaxf(acc3[r]/rsc[n] + hg[n*D1 + o], 0.f);
            hg[n*D1 + D2 + o] = h2v;
            part2[r] = h2v * wpool2v;
        }
        #pragma unroll
        for (int r = 0; r < CR; r++) {
            float v = part2[r];
            #pragma unroll
            for (int off = 32; off; off >>= 1) v += __shfl_xor(v, off, 64);
            if (lane == 0) redc[wave*CR + r] = v;
        }
    }
    __syncthreads();
    {
        const float bpool2v = bpool2[0];
        if (tid < KP1) {
            int hh = tid / CR, rr = tid - hh*CR;
            float s = redc[(2*hh)*CR + rr] + redc[(2*hh+1)*CR + rr];
            sc2[tid] = sigm(s + bpool2v);
        }
    }
    __syncthreads();

    if (tid < 64) topk_wave(sc2, KP1, KP2, idx2, vals2, tid);
    __syncthreads();

    if (tid < D2) {
        float m = 0.f;
        for (int k = 0; k < KP2; k++) m += hg[idx2[k]*D1 + D2 + tid] * vals2[k];
        hmean[tid] = m * (1.f/28.f);
    }
    __syncthreads();

    if (tid < 64) {
        float s = 0.f;
        for (int d = 0; d < D2; d++) s += hmean[d] * Wfc1[tid*D2 + d];
        s = fmaxf(s + bfc1[tid], 0.f);
        float v = s * Wfc2[tid];
        #pragma unroll
        for (int off = 32; off; off >>= 1) v += __shfl_xor(v, off, 64);
        if (tid == 0) out[b] = v + bfc2[0];
    }
}

extern "C" void kernel_launch(void* const* d_in, const int* in_sizes, int n_in,
                              void* d_out, int out_size, void* d_ws, size_t ws_size,
                              hipStream_t stream) {
    (void)in_sizes; (void)n_in; (void)out_size;
    fp x      = (fp)d_in[0];
    fp Wp1    = (fp)d_in[1];
    fp bp1    = (fp)d_in[2];
    fp wa1    = (fp)d_in[3];
    fp wb1    = (fp)d_in[4];
    fp ba1    = (fp)d_in[5];
    fp Wpool1 = (fp)d_in[6];
    fp bpool1 = (fp)d_in[7];
    fp Wp2    = (fp)d_in[8];
    fp bp2    = (fp)d_in[9];
    fp wa2    = (fp)d_in[10];
    fp wb2    = (fp)d_in[11];
    fp ba2    = (fp)d_in[12];
    fp Wpool2 = (fp)d_in[13];
    fp bpool2 = (fp)d_in[14];
    fp Wfc1   = (fp)d_in[15];
    fp bfc1   = (fp)d_in[16];
    fp Wfc2   = (fp)d_in[17];
    fp bfc2   = (fp)d_in[18];

    const size_t WS_NEED = (size_t)(NODE*D1 + NODE*NODE + D1*D2 + 2*NODE) * sizeof(float);

    if (ws_size >= WS_NEED) {
        float* hp  = (float*)d_ws;          // [112][256]
        float* E1  = hp  + NODE*D1;         // [112][112]
        float* W2T = E1  + NODE*NODE;       // [256][128]
        float* s1  = W2T + D1*D2;           // [112]
        float* t1  = s1  + NODE;            // [112]
        hipLaunchKernelGGL(k0a, dim3(1), dim3(256), 0, stream,
                           Wp1, bp1, wa1, wb1, s1, t1);
        hipLaunchKernelGGL(k0b, dim3(64), dim3(256), 0, stream,
                           Wp1, bp1, ba1, Wp2, s1, t1, hp, E1, W2T);
        hipLaunchKernelGGL(gnn_fast, dim3(NBATCH), dim3(256), 0, stream,
                           x, Wpool1, bpool1, bp2, wa2, wb2, ba2,
                           Wpool2, bpool2, Wfc1, bfc1, Wfc2, bfc2,
                           hp, E1, W2T, (float*)d_out);
    } else {
        hipLaunchKernelGGL(gnn_fallback, dim3(NBATCH), dim3(256), 0, stream,
                           x, Wp1, bp1, wa1, wb1, ba1, Wpool1, bpool1,
                           Wp2, bp2, wa2, wb2, ba2, Wpool2, bpool2,
                           Wfc1, bfc1, Wfc2, bfc2, (float*)d_out);
    }
}

// Round 7
// 754.060 us; speedup vs baseline: 1.8639x; 1.8639x over previous
//
#include <hip/hip_runtime.h>

#define NODE 112
#define KP1 56
#define KP2 28
#define D1 256
#define D2 128
#define NBATCH 2048
#define NCH 4      // phase-1 chunks
#define WR 7       // rows per wave per chunk (live accumulators = 28 -> no spill)
#define GR 7       // rows per group in phase-3/4b
#define CR 28      // fallback: rows per chunk

typedef const float* __restrict__ fp;

// ---------------- K0a: batch-independent attention logits s1[n], t1[n] ----------------
__global__ void k0a(fp Wp1, fp bp1, fp wa1, fp wb1,
                    float* __restrict__ s1, float* __restrict__ t1)
{
    int tid = threadIdx.x;
    int i = tid >> 1, half = tid & 1;
    float sa = 0.f, sb = 0.f;
    if (i < NODE) {
        for (int o = half*128; o < half*128 + 128; o++) {
            float h = Wp1[o*NODE + i] + bp1[o];
            sa += h * wa1[o];
            sb += h * wb1[o];
        }
    }
    sa += __shfl_xor(sa, 1, 64);
    sb += __shfl_xor(sb, 1, 64);
    if (i < NODE && half == 0) { s1[i] = sa; t1[i] = sb; }
}

// ---------------- K0b: hp [112][256], E1 [112][112], W2T [256][128] ----------------
__global__ void k0b(fp Wp1, fp bp1, fp ba1, fp Wp2,
                    const float* __restrict__ s1, const float* __restrict__ t1,
                    float* __restrict__ hp, float* __restrict__ E1, float* __restrict__ W2T)
{
    int g = blockIdx.x*blockDim.x + threadIdx.x;
    int stride = gridDim.x*blockDim.x;
    for (int e = g; e < NODE*D1; e += stride) {
        int j = e >> 8, o = e & 255;
        hp[e] = Wp1[o*NODE + j] + bp1[o];
    }
    float ba = ba1[0];
    for (int e = g; e < NODE*NODE; e += stride) {
        int i = e / NODE, j = e - i*NODE;
        E1[e] = expf(fmaxf(s1[i] + t1[j] + ba, 0.f));
    }
    for (int e = g; e < D1*D2; e += stride) {
        int d = e >> 7, o = e & 127;
        W2T[e] = Wp2[o*D1 + d];
    }
}

// wave-0 top-k with jax.lax.top_k tie semantics (equal value -> lower index first)
__device__ __forceinline__ void topk_wave(volatile float* sc, int n, int k,
                                          int* idxo, float* valo, int tid)
{
    for (int it = 0; it < k; it++) {
        float v = (tid < n) ? sc[tid] : -1e30f;
        int bi = tid;
        int j2 = tid + 64;
        if (j2 < n) { float v2 = sc[j2]; if (v2 > v) { v = v2; bi = j2; } }
        #pragma unroll
        for (int off = 32; off; off >>= 1) {
            float ov = __shfl_xor(v, off, 64);
            int   oi = __shfl_xor(bi, off, 64);
            if (ov > v || (ov == v && oi < bi)) { v = ov; bi = oi; }
        }
        if (tid == 0) { idxo[it] = bi; valo[it] = v; sc[bi] = -1e30f; }
    }
}

__device__ __forceinline__ float sigm(float v) { return 1.f/(1.f + expf(-v)); }

// ===================== FAST PATH =====================
__global__ __launch_bounds__(256, 2) void gnn_fast(
    fp x, fp Wpool1, fp bpool1, fp bp2, fp wa2, fp wb2, fp ba2,
    fp Wpool2, fp bpool2, fp Wfc1, fp bfc1, fp Wfc2, fp bfc2,
    fp hp, fp E1, fp W2T, float* __restrict__ out)
{
    // ovl: phase-1 awcF[112*112] (50176 B), then hg[56*256] (57344 B) after top-k.
    __shared__ __align__(16) float ovl[KP1*D1];
    __shared__ __align__(16) float awc2[KP1*KP1];   // att2 [56][56]
    __shared__ float rinv[NODE];
    __shared__ float sc1[NODE];
    __shared__ int   idx1[KP1];
    __shared__ float vals1[KP1];
    __shared__ int   sel[NODE];
    __shared__ float s2v[KP1], t2v[KP1];
    __shared__ float rs2inv[KP1];
    __shared__ float sc2[KP1];
    __shared__ int   idx2[KP2];
    __shared__ float vals2[KP2];
    __shared__ float hmean[D2];

    float* awcF = ovl;     // [112][112] attention weights (phase 1)
    float* hg   = ovl;     // [56][256] gathered h1 -> h2proj/h2 (after top-k)

    const int tid = threadIdx.x;
    const int lane = tid & 63, wave = tid >> 6;
    const int b = blockIdx.x;
    const float* xb = x + (size_t)b*NODE*NODE;

    const float4 wp1v = *(const float4*)(Wpool1 + 4*lane);
    const float bpool1v = bpool1[0];

    // ========== Phase 1 fill: awcF[i][j] = E1[i][j]*x[i][j], fold row sums ==========
    // 4 threads/row (seg = tid&3, 28 floats each). Coalesced and conflict-free.
    {
        const int seg = tid & 3;
        #pragma unroll
        for (int pass = 0; pass < 2; pass++) {
            const int i = (tid >> 2) + pass*64;
            float ps = 0.f;
            if (i < NODE) {
                const float4* Er = (const float4*)(E1 + i*NODE + seg*28);
                const float4* xr = (const float4*)(xb + i*NODE + seg*28);
                float4* ar = (float4*)(awcF + i*NODE + seg*28);
                #pragma unroll
                for (int q = 0; q < 7; q++) {
                    float4 e = Er[q], xv = xr[q];
                    float4 v = make_float4(e.x*xv.x, e.y*xv.y, e.z*xv.z, e.w*xv.w);
                    ar[q] = v;
                    ps += (v.x + v.y) + (v.z + v.w);
                }
            }
            ps += __shfl_xor(ps, 1, 64);
            ps += __shfl_xor(ps, 2, 64);
            if (i < NODE && seg == 0) rinv[i] = 1.f/ps;
        }
    }
    __syncthreads();

    // ========== Phase 1 GEMM: 4 chunks x 7 rows/wave (<=28 live accumulators per
    // back-edge -- R6's 112-live-acc form spilled to scratch: 2.4 GB WRITE_SIZE).
    // awcF fully resident -> no barriers inside the chunk loop. lane owns cols 4l..4l+3.
    const int r0 = wave*WR;
    float h1r[NCH][WR][4];   // persistent h1 (static indices only!)
    #pragma unroll
    for (int c = 0; c < NCH; c++) {
        float acc[WR][4];
        #pragma unroll
        for (int r = 0; r < WR; r++) { acc[r][0]=0.f; acc[r][1]=0.f; acc[r][2]=0.f; acc[r][3]=0.f; }
        #pragma unroll 2
        for (int jq = 0; jq < NODE/4; jq++) {
            const int j = jq*4;
            float4 hv0 = *(const float4*)(hp + (j+0)*D1 + 4*lane);
            float4 hv1 = *(const float4*)(hp + (j+1)*D1 + 4*lane);
            float4 hv2 = *(const float4*)(hp + (j+2)*D1 + 4*lane);
            float4 hv3 = *(const float4*)(hp + (j+3)*D1 + 4*lane);
            #pragma unroll
            for (int r = 0; r < WR; r++) {
                float4 a4 = *(const float4*)&awcF[(c*CR + r0 + r)*NODE + j];
                acc[r][0] += a4.x*hv0.x + a4.y*hv1.x + a4.z*hv2.x + a4.w*hv3.x;
                acc[r][1] += a4.x*hv0.y + a4.y*hv1.y + a4.z*hv2.y + a4.w*hv3.y;
                acc[r][2] += a4.x*hv0.z + a4.y*hv1.z + a4.z*hv2.z + a4.w*hv3.z;
                acc[r][3] += a4.x*hv0.w + a4.y*hv1.w + a4.z*hv2.w + a4.w*hv3.w;
            }
        }
        // epilogue: h1 = relu(acc*rinv + hp[i]); pool1 scores
        #pragma unroll
        for (int r = 0; r < WR; r++) {
            const int i = c*CR + r0 + r;
            const float ri = rinv[i];
            float4 hpi = *(const float4*)(hp + i*D1 + 4*lane);
            float v0 = fmaxf(acc[r][0]*ri + hpi.x, 0.f);
            float v1 = fmaxf(acc[r][1]*ri + hpi.y, 0.f);
            float v2 = fmaxf(acc[r][2]*ri + hpi.z, 0.f);
            float v3 = fmaxf(acc[r][3]*ri + hpi.w, 0.f);
            h1r[c][r][0]=v0; h1r[c][r][1]=v1; h1r[c][r][2]=v2; h1r[c][r][3]=v3;
            float p = v0*wp1v.x + v1*wp1v.y + v2*wp1v.z + v3*wp1v.w;
            #pragma unroll
            for (int off = 32; off; off >>= 1) p += __shfl_xor(p, off, 64);
            if (lane == 0) sc1[i] = sigm(p + bpool1v);
        }
    }
    __syncthreads();   // all awcF reads done; sc1 complete

    // ========== top-56 (wave 0) + sel init (wave 2) ==========
    if (tid < 64) topk_wave(sc1, NODE, KP1, idx1, vals1, tid);
    else if (tid >= 128 && tid < 128 + NODE) sel[tid - 128] = -1;
    __syncthreads();
    if (tid < KP1) sel[idx1[tid]] = tid;
    __syncthreads();

    // ========== scatter selected h1 rows (scaled) into hg (overwrites awcF) ==========
    #pragma unroll
    for (int c = 0; c < NCH; c++) {
        #pragma unroll
        for (int r = 0; r < WR; r++) {
            const int i = c*CR + r0 + r;
            const int k = sel[i];                 // wave-uniform
            if (k >= 0) {
                const float vs = vals1[k];
                *(float4*)&hg[k*D1 + 4*lane] =
                    make_float4(h1r[c][r][0]*vs, h1r[c][r][1]*vs,
                                h1r[c][r][2]*vs, h1r[c][r][3]*vs);
            }
        }
    }
    __syncthreads();

    // ========== Phase 3: h2proj = hg@W2T + bp2 -> hg cols 0..127 ==========
    {
        const int g = tid >> 5;          // 8 groups x 7 rows
        const int cs = tid & 31;         // cols 4cs..4cs+3 of 128
        float acc2[GR][4];
        #pragma unroll
        for (int r = 0; r < GR; r++) { acc2[r][0]=0.f; acc2[r][1]=0.f; acc2[r][2]=0.f; acc2[r][3]=0.f; }
        #pragma unroll 2
        for (int dq = 0; dq < D1/4; dq++) {
            const int d = dq*4;
            float4 w0 = *(const float4*)(W2T + (d+0)*D2 + 4*cs);
            float4 w1 = *(const float4*)(W2T + (d+1)*D2 + 4*cs);
            float4 w2 = *(const float4*)(W2T + (d+2)*D2 + 4*cs);
            float4 w3 = *(const float4*)(W2T + (d+3)*D2 + 4*cs);
            #pragma unroll
            for (int r = 0; r < GR; r++) {
                float4 a4 = *(const float4*)&hg[(g*GR+r)*D1 + d];
                acc2[r][0] += a4.x*w0.x + a4.y*w1.x + a4.z*w2.x + a4.w*w3.x;
                acc2[r][1] += a4.x*w0.y + a4.y*w1.y + a4.z*w2.y + a4.w*w3.y;
                acc2[r][2] += a4.x*w0.z + a4.y*w1.z + a4.z*w2.z + a4.w*w3.z;
                acc2[r][3] += a4.x*w0.w + a4.y*w1.w + a4.z*w2.w + a4.w*w3.w;
            }
        }
        float4 b2 = *(const float4*)(bp2 + 4*cs);
        __syncthreads();   // all hg reads complete before overwrite
        #pragma unroll
        for (int r = 0; r < GR; r++) {
            *(float4*)&hg[(g*GR+r)*D1 + 4*cs] =
                make_float4(acc2[r][0]+b2.x, acc2[r][1]+b2.y, acc2[r][2]+b2.z, acc2[r][3]+b2.w);
        }
    }
    __syncthreads();

    // ========== Phase 3.5: s2[n], t2[n] ==========
    if (tid < 4*KP1) {
        int row = tid >> 2, seg = tid & 3;       // 4 threads/row, 32 cols each
        float sa = 0.f, sb = 0.f;
        #pragma unroll
        for (int q = 0; q < 8; q++) {
            float4 hv = *(const float4*)&hg[row*D1 + seg*32 + q*4];
            float4 va = *(const float4*)(wa2 + seg*32 + q*4);
            float4 vb = *(const float4*)(wb2 + seg*32 + q*4);
            sa += hv.x*va.x + hv.y*va.y + hv.z*va.z + hv.w*va.w;
            sb += hv.x*vb.x + hv.y*vb.y + hv.z*vb.z + hv.w*vb.w;
        }
        sa += __shfl_xor(sa, 1, 64); sa += __shfl_xor(sa, 2, 64);
        sb += __shfl_xor(sb, 1, 64); sb += __shfl_xor(sb, 2, 64);
        if (seg == 0) { s2v[row] = sa; t2v[row] = sb; }
    }
    __syncthreads();

    // ========== Phase 4a: att2 fill (pool1 row-norm cancels) + row sums ==========
    if (tid < 4*KP1) {
        int rloc = tid >> 2, seg = tid & 3;      // 4 threads/row, 14 cols each
        float ps = 0.f;
        int gi = idx1[rloc];
        float srow = s2v[rloc];
        const float ba2v = ba2[0];
        const float* xrow = xb + gi*NODE;
        float* arow = awc2 + rloc*KP1 + seg*14;
        #pragma unroll
        for (int q = 0; q < 14; q++) {
            int j = seg*14 + q;
            float e = fmaxf(srow + t2v[j] + ba2v, 0.f);
            float v = expf(e) * xrow[idx1[j]];
            arow[q] = v;
            ps += v;
        }
        ps += __shfl_xor(ps, 1, 64); ps += __shfl_xor(ps, 2, 64);
        if (seg == 0) rs2inv[rloc] = 1.f/ps;
    }
    __syncthreads();

    // ========== Phase 4b: h2 = relu(att2@h2proj + h2proj) -> hg cols 128..255 ==========
    {
        const int g = tid >> 5, cs = tid & 31;
        float acc3[GR][4];
        #pragma unroll
        for (int r = 0; r < GR; r++) { acc3[r][0]=0.f; acc3[r][1]=0.f; acc3[r][2]=0.f; acc3[r][3]=0.f; }
        #pragma unroll 2
        for (int lq = 0; lq < KP1/4; lq++) {
            const int l = lq*4;
            float4 p0 = *(const float4*)&hg[(l+0)*D1 + 4*cs];
            float4 p1 = *(const float4*)&hg[(l+1)*D1 + 4*cs];
            float4 p2 = *(const float4*)&hg[(l+2)*D1 + 4*cs];
            float4 p3 = *(const float4*)&hg[(l+3)*D1 + 4*cs];
            #pragma unroll
            for (int r = 0; r < GR; r++) {
                float4 a4 = *(const float4*)&awc2[(g*GR+r)*KP1 + l];
                acc3[r][0] += a4.x*p0.x + a4.y*p1.x + a4.z*p2.x + a4.w*p3.x;
                acc3[r][1] += a4.x*p0.y + a4.y*p1.y + a4.z*p2.y + a4.w*p3.y;
                acc3[r][2] += a4.x*p0.z + a4.y*p1.z + a4.z*p2.z + a4.w*p3.z;
                acc3[r][3] += a4.x*p0.w + a4.y*p1.w + a4.z*p2.w + a4.w*p3.w;
            }
        }
        const float4 wp2v = *(const float4*)(Wpool2 + 4*cs);
        const float bpool2v = bpool2[0];
        #pragma unroll
        for (int r = 0; r < GR; r++) {
            int row = g*GR + r;
            float ri = rs2inv[row];
            float4 hpj = *(const float4*)&hg[row*D1 + 4*cs];       // residual (cols 0..127)
            float v0 = fmaxf(acc3[r][0]*ri + hpj.x, 0.f);
            float v1 = fmaxf(acc3[r][1]*ri + hpj.y, 0.f);
            float v2 = fmaxf(acc3[r][2]*ri + hpj.z, 0.f);
            float v3 = fmaxf(acc3[r][3]*ri + hpj.w, 0.f);
            *(float4*)&hg[row*D1 + D2 + 4*cs] = make_float4(v0, v1, v2, v3);
            float p = v0*wp2v.x + v1*wp2v.y + v2*wp2v.z + v3*wp2v.w;
            p += __shfl_xor(p, 16, 64); p += __shfl_xor(p, 8, 64);
            p += __shfl_xor(p, 4, 64);  p += __shfl_xor(p, 2, 64);
            p += __shfl_xor(p, 1, 64);
            if (cs == 0) sc2[row] = sigm(p + bpool2v);
        }
    }
    __syncthreads();

    // ========== top-28 ==========
    if (tid < 64) topk_wave(sc2, KP1, KP2, idx2, vals2, tid);
    __syncthreads();

    // ========== Phase 6: weighted mean over pooled nodes ==========
    if (tid < D2) {
        float m = 0.f;
        for (int k = 0; k < KP2; k++) m += hg[idx2[k]*D1 + D2 + tid] * vals2[k];
        hmean[tid] = m * (1.f/28.f);
    }
    __syncthreads();

    // ========== Phase 7: FC head ==========
    if (tid < 64) {
        float s = 0.f;
        #pragma unroll
        for (int q = 0; q < 32; q++) {
            float4 w = *(const float4*)(Wfc1 + tid*D2 + q*4);
            s += hmean[q*4+0]*w.x + hmean[q*4+1]*w.y + hmean[q*4+2]*w.z + hmean[q*4+3]*w.w;
        }
        s = fmaxf(s + bfc1[tid], 0.f);
        float v = s * Wfc2[tid];
        #pragma unroll
        for (int off = 32; off; off >>= 1) v += __shfl_xor(v, off, 64);
        if (tid == 0) out[b] = v + bfc2[0];
    }
}

// ===================== FALLBACK (round-3 kernel, passed) =====================
__global__ __launch_bounds__(256) void gnn_fallback(
    fp x, fp Wp1, fp bp1, fp wa1, fp wb1, fp ba1,
    fp Wpool1, fp bpool1, fp Wp2, fp bp2, fp wa2, fp wb2, fp ba2,
    fp Wpool2, fp bpool2, fp Wfc1, fp bfc1, fp Wfc2, fp bfc2,
    float* __restrict__ out)
{
    __shared__ __align__(16) float hg[KP1*D1];
    __shared__ __align__(16) float awc[CR*NODE];
    __shared__ float s1v[NODE], t1v[NODE];
    __shared__ float sc1[NODE];
    __shared__ float rsc[KP1];
    __shared__ float redc[4*CR];
    __shared__ int   idx1[KP1];
    __shared__ float vals1[KP1];
    __shared__ float s2v[KP1], t2v[KP1];
    __shared__ float sc2[KP1];
    __shared__ int   idx2[KP2];
    __shared__ float vals2[KP2];
    __shared__ float hmean[D2];

    const int tid = threadIdx.x;
    const int lane = tid & 63, wave = tid >> 6;
    const int b = blockIdx.x;
    const float* xb = x + (size_t)b*NODE*NODE;

    const float wpool1v = Wpool1[tid];
    const float bpool1v = bpool1[0];
    const float ba1v    = ba1[0];
    const float* wrow = Wp1 + tid*NODE;
    const float bp1v = bp1[tid];

    if (tid < NODE) {
        float sa = 0.f, sb = 0.f;
        for (int o = 0; o < D1; o++) {
            float h = Wp1[o*NODE + tid] + bp1[o];
            sa += h * wa1[o];
            sb += h * wb1[o];
        }
        s1v[tid] = sa; t1v[tid] = sb;
    }
    __syncthreads();

    for (int c = 0; c < NODE/CR; c++) {
        const int i0 = c*CR;
        for (int e = tid; e < CR*NODE; e += 256) {
            int r = e / NODE, j = e - r*NODE;
            int i = i0 + r;
            float ee = fmaxf(s1v[i] + t1v[j] + ba1v, 0.f);
            awc[e] = expf(ee) * xb[i*NODE + j];
        }
        __syncthreads();
        if (tid < CR) {
            float s = 0.f;
            for (int j = 0; j < NODE; j++) s += awc[tid*NODE + j];
            rsc[tid] = s;
        }
        __syncthreads();
        float acc[CR];
        #pragma unroll
        for (int r = 0; r < CR; r++) acc[r] = 0.f;
        for (int jg = 0; jg < NODE/4; jg++) {
            float4 w = *(const float4*)(wrow + jg*4);
            float h0 = w.x + bp1v, h1 = w.y + bp1v, h2 = w.z + bp1v, h3 = w.w + bp1v;
            #pragma unroll
            for (int r = 0; r < CR; r++) {
                float4 a4 = *(const float4*)&awc[r*NODE + jg*4];
                acc[r] += a4.x*h0 + a4.y*h1 + a4.z*h2 + a4.w*h3;
            }
        }
        float part[CR];
        #pragma unroll
        for (int r = 0; r < CR; r++) {
            float hpi = wrow[i0 + r] + bp1v;
            float h1v = fmaxf(acc[r]/rsc[r] + hpi, 0.f);
            part[r] = h1v * wpool1v;
        }
        #pragma unroll
        for (int r = 0; r < CR; r++) {
            float v = part[r];
            #pragma unroll
            for (int off = 32; off; off >>= 1) v += __shfl_xor(v, off, 64);
            if (lane == 0) redc[wave*CR + r] = v;
        }
        __syncthreads();
        if (tid < CR) {
            float s = redc[tid] + redc[CR+tid] + redc[2*CR+tid] + redc[3*CR+tid];
            sc1[i0 + tid] = sigm(s + bpool1v);
        }
        __syncthreads();
    }

    if (tid < 64) topk_wave(sc1, NODE, KP1, idx1, vals1, tid);
    __syncthreads();

    for (int c = 0; c < KP1/CR; c++) {
        const int k0 = c*CR;
        for (int e = tid; e < CR*NODE; e += 256) {
            int r = e / NODE, j = e - r*NODE;
            int i = idx1[k0 + r];
            float ee = fmaxf(s1v[i] + t1v[j] + ba1v, 0.f);
            awc[e] = expf(ee) * xb[i*NODE + j];
        }
        __syncthreads();
        if (tid < CR) {
            float s = 0.f;
            for (int j = 0; j < NODE; j++) s += awc[tid*NODE + j];
            rsc[tid] = s;
        }
        __syncthreads();
        float acc[CR];
        #pragma unroll
        for (int r = 0; r < CR; r++) acc[r] = 0.f;
        for (int jg = 0; jg < NODE/4; jg++) {
            float4 w = *(const float4*)(wrow + jg*4);
            float h0 = w.x + bp1v, h1 = w.y + bp1v, h2 = w.z + bp1v, h3 = w.w + bp1v;
            #pragma unroll
            for (int r = 0; r < CR; r++) {
                float4 a4 = *(const float4*)&awc[r*NODE + jg*4];
                acc[r] += a4.x*h0 + a4.y*h1 + a4.z*h2 + a4.w*h3;
            }
        }
        #pragma unroll
        for (int r = 0; r < CR; r++) {
            int k = k0 + r;
            float hpi = wrow[idx1[k]] + bp1v;
            float h1v = fmaxf(acc[r]/rsc[r] + hpi, 0.f);
            hg[k*D1 + tid] = h1v * vals1[k];
        }
        __syncthreads();
    }

    {
        const int half = tid >> 7, o = tid & 127;
        const float* w2row = Wp2 + o*D1;
        float acc2[CR];
        #pragma unroll
        for (int r = 0; r < CR; r++) acc2[r] = 0.f;
        for (int d4 = 0; d4 < D1; d4 += 4) {
            float4 w = *(const float4*)(w2row + d4);
            #pragma unroll
            for (int r = 0; r < CR; r++) {
                float4 h4 = *(const float4*)&hg[(half*CR + r)*D1 + d4];
                acc2[r] += h4.x*w.x + h4.y*w.y + h4.z*w.z + h4.w*w.w;
            }
        }
        __syncthreads();
        float bp2v = bp2[o];
        #pragma unroll
        for (int r = 0; r < CR; r++)
            hg[(half*CR + r)*D1 + o] = acc2[r] + bp2v;
    }
    __syncthreads();

    if (tid < KP1) {
        float sa = 0.f, sb = 0.f;
        for (int o2 = 0; o2 < D2; o2++) {
            float hv = hg[tid*D1 + o2];
            sa += hv * wa2[o2];
            sb += hv * wb2[o2];
        }
        s2v[tid] = sa; t2v[tid] = sb;
    }
    __syncthreads();

    {
        const float ba2v = ba2[0];
        for (int e = tid; e < KP1*KP1; e += 256) {
            int i = e / KP1, j = e - i*KP1;
            float ee = fmaxf(s2v[i] + t2v[j] + ba2v, 0.f);
            awc[e] = expf(ee) * xb[idx1[i]*NODE + idx1[j]];
        }
    }
    __syncthreads();
    if (tid < KP1) {
        float s = 0.f;
        for (int j = 0; j < KP1; j++) s += awc[tid*KP1 + j];
        rsc[tid] = s;
    }
    __syncthreads();

    {
        const int half = tid >> 7, o = tid & 127;
        float acc3[CR];
        #pragma unroll
        for (int r = 0; r < CR; r++) acc3[r] = 0.f;
        for (int l4 = 0; l4 < KP1; l4 += 4) {
            float p0 = hg[(l4+0)*D1 + o];
            float p1 = hg[(l4+1)*D1 + o];
            float p2 = hg[(l4+2)*D1 + o];
            float p3 = hg[(l4+3)*D1 + o];
            #pragma unroll
            for (int r = 0; r < CR; r++) {
                float4 a4 = *(const float4*)&awc[(half*CR + r)*KP1 + l4];
                acc3[r] += a4.x*p0 + a4.y*p1 + a4.z*p2 + a4.w*p3;
            }
        }
        const float wpool2v = Wpool2[o];
        float part2[CR];
        #pragma unroll
        for (int r = 0; r < CR; r++) {
            int n = half*CR + r;
            float h2v = fmaxf(acc3[r]/rsc[n] + hg[n*D1 + o], 0.f);
            hg[n*D1 + D2 + o] = h2v;
            part2[r] = h2v * wpool2v;
        }
        #pragma unroll
        for (int r = 0; r < CR; r++) {
            float v = part2[r];
            #pragma unroll
            for (int off = 32; off; off >>= 1) v += __shfl_xor(v, off, 64);
            if (lane == 0) redc[wave*CR + r] = v;
        }
    }
    __syncthreads();
    {
        const float bpool2v = bpool2[0];
        if (tid < KP1) {
            int hh = tid / CR, rr = tid - hh*CR;
            float s = redc[(2*hh)*CR + rr] + redc[(2*hh+1)*CR + rr];
            sc2[tid] = sigm(s + bpool2v);
        }
    }
    __syncthreads();

    if (tid < 64) topk_wave(sc2, KP1, KP2, idx2, vals2, tid);
    __syncthreads();

    if (tid < D2) {
        float m = 0.f;
        for (int k = 0; k < KP2; k++) m += hg[idx2[k]*D1 + D2 + tid] * vals2[k];
        hmean[tid] = m * (1.f/28.f);
    }
    __syncthreads();

    if (tid < 64) {
        float s = 0.f;
        for (int d = 0; d < D2; d++) s += hmean[d] * Wfc1[tid*D2 + d];
        s = fmaxf(s + bfc1[tid], 0.f);
        float v = s * Wfc2[tid];
        #pragma unroll
        for (int off = 32; off; off >>= 1) v += __shfl_xor(v, off, 64);
        if (tid == 0) out[b] = v + bfc2[0];
    }
}

extern "C" void kernel_launch(void* const* d_in, const int* in_sizes, int n_in,
                              void* d_out, int out_size, void* d_ws, size_t ws_size,
                              hipStream_t stream) {
    (void)in_sizes; (void)n_in; (void)out_size;
    fp x      = (fp)d_in[0];
    fp Wp1    = (fp)d_in[1];
    fp bp1    = (fp)d_in[2];
    fp wa1    = (fp)d_in[3];
    fp wb1    = (fp)d_in[4];
    fp ba1    = (fp)d_in[5];
    fp Wpool1 = (fp)d_in[6];
    fp bpool1 = (fp)d_in[7];
    fp Wp2    = (fp)d_in[8];
    fp bp2    = (fp)d_in[9];
    fp wa2    = (fp)d_in[10];
    fp wb2    = (fp)d_in[11];
    fp ba2    = (fp)d_in[12];
    fp Wpool2 = (fp)d_in[13];
    fp bpool2 = (fp)d_in[14];
    fp Wfc1   = (fp)d_in[15];
    fp bfc1   = (fp)d_in[16];
    fp Wfc2   = (fp)d_in[17];
    fp bfc2   = (fp)d_in[18];

    const size_t WS_NEED = (size_t)(NODE*D1 + NODE*NODE + D1*D2 + 2*NODE) * sizeof(float);

    if (ws_size >= WS_NEED) {
        float* hp  = (float*)d_ws;          // [112][256]
        float* E1  = hp  + NODE*D1;         // [112][112]
        float* W2T = E1  + NODE*NODE;       // [256][128]
        float* s1  = W2T + D1*D2;           // [112]
        float* t1  = s1  + NODE;            // [112]
        hipLaunchKernelGGL(k0a, dim3(1), dim3(256), 0, stream,
                           Wp1, bp1, wa1, wb1, s1, t1);
        hipLaunchKernelGGL(k0b, dim3(64), dim3(256), 0, stream,
                           Wp1, bp1, ba1, Wp2, s1, t1, hp, E1, W2T);
        hipLaunchKernelGGL(gnn_fast, dim3(NBATCH), dim3(256), 0, stream,
                           x, Wpool1, bpool1, bp2, wa2, wb2, ba2,
                           Wpool2, bpool2, Wfc1, bfc1, Wfc2, bfc2,
                           hp, E1, W2T, (float*)d_out);
    } else {
        hipLaunchKernelGGL(gnn_fallback, dim3(NBATCH), dim3(256), 0, stream,
                           x, Wp1, bp1, wa1, wb1, ba1, Wpool1, bpool1,
                           Wp2, bp2, wa2, wb2, ba2, Wpool2, bpool2,
                           Wfc1, bfc1, Wfc2, bfc2, (float*)d_out);
    }
}